// Round 5
// baseline (846.962 us; speedup 1.0000x reference)
//
#include <hip/hip_runtime.h>
#include <stdint.h>

typedef unsigned short u16;
typedef short short8 __attribute__((ext_vector_type(8)));
typedef short short4v __attribute__((ext_vector_type(4)));
typedef float floatx4 __attribute__((ext_vector_type(4)));

#define D_FEAT 256

__device__ __forceinline__ u16 f2bf(float x){
  unsigned u = __float_as_uint(x);
  u += 0x7FFFu + ((u >> 16) & 1u);   // round-to-nearest-even
  return (u16)(u >> 16);
}

__device__ __forceinline__ short8 pack8(float4 a, float4 b){
  short8 v;
  v[0]=(short)f2bf(a.x); v[1]=(short)f2bf(a.y); v[2]=(short)f2bf(a.z); v[3]=(short)f2bf(a.w);
  v[4]=(short)f2bf(b.x); v[5]=(short)f2bf(b.y); v[6]=(short)f2bf(b.z); v[7]=(short)f2bf(b.w);
  return v;
}

// wt[n*K + k] = bf16(w[k*N + n])  -- transpose so B-fragments are contiguous in K
__global__ void conv_t_kernel(const float* __restrict__ w, u16* __restrict__ wt, int K, int N){
  int idx = blockIdx.x * 256 + threadIdx.x;
  if (idx >= K * N) return;
  int k = idx / N, n = idx - k * N;
  wt[(size_t)n * K + k] = f2bf(w[idx]);
}

// ---------------- CSR build ----------------
__global__ void hist_kernel(const int* __restrict__ didx, int E, int* __restrict__ cnt){
  int e = blockIdx.x * 256 + threadIdx.x;
  if (e < E) atomicAdd(&cnt[didx[e]], 1);
}

__global__ void scan_block_kernel(const int* __restrict__ cnt, int* __restrict__ excl,
                                  int* __restrict__ bsums, int N){
  __shared__ int tmp[256];
  int t = threadIdx.x;
  int i = blockIdx.x * 256 + t;
  int v = (i < N) ? cnt[i] : 0;
  tmp[t] = v; __syncthreads();
#pragma unroll
  for (int o = 1; o < 256; o <<= 1){
    int x = (t >= o) ? tmp[t - o] : 0;
    __syncthreads();
    tmp[t] += x;
    __syncthreads();
  }
  if (i < N) excl[i] = tmp[t] - v;
  if (t == 255) bsums[blockIdx.x] = tmp[255];
}

// parallel exclusive scan of block sums (nb <= 512 in practice; serial fallback otherwise)
__global__ void scan_bsums_kernel(int* __restrict__ bsums, int nb){
  __shared__ int tmp[512];
  int t = threadIdx.x;
  if (nb > 512){
    if (t == 0){
      int acc = 0;
      for (int i = 0; i < nb; i++){ int v = bsums[i]; bsums[i] = acc; acc += v; }
    }
    return;
  }
  int v = (t < nb) ? bsums[t] : 0;
  tmp[t] = v; __syncthreads();
#pragma unroll
  for (int o = 1; o < 512; o <<= 1){
    int x = (t >= o) ? tmp[t - o] : 0;
    __syncthreads();
    tmp[t] += x;
    __syncthreads();
  }
  if (t < nb) bsums[t] = tmp[t] - v;
}

// adds block offsets AND initializes fillc = row_start (removes fillc memset)
__global__ void scan_add_kernel(int* __restrict__ excl, const int* __restrict__ bsums,
                                int* __restrict__ fillc, int N){
  int i = blockIdx.x * 256 + threadIdx.x;
  if (i < N){
    int v = excl[i] + bsums[blockIdx.x];
    excl[i] = v;
    fillc[i] = v;
  }
}

// fillc holds absolute positions (pre-initialized to row_start)
__global__ void fill_csr_kernel(const int* __restrict__ sidx, const int* __restrict__ didx, int E,
                                int* __restrict__ fillc, int* __restrict__ esrc){
  int e = blockIdx.x * 256 + threadIdx.x;
  if (e >= E) return;
  int pos = atomicAdd(&fillc[didx[e]], 1);
  esrc[pos] = sidx[e];
}

// one wave per dst row: gather src rows, accumulate fp32, write mean as bf16
__global__ void agg_mean_kernel(const float* __restrict__ feat, const int* __restrict__ row_start,
                                const int* __restrict__ cnt, const int* __restrict__ esrc,
                                u16* __restrict__ mean, int M){
  int row = blockIdx.x * 4 + (threadIdx.x >> 6);
  int lane = threadIdx.x & 63;
  if (row >= M) return;
  int beg = row_start[row], n = cnt[row];
  float4 a0 = {0.f,0.f,0.f,0.f}, a1 = {0.f,0.f,0.f,0.f};
  int j = 0;
  for (; j + 1 < n; j += 2){
    int s0 = esrc[beg + j], s1 = esrc[beg + j + 1];
    float4 v0 = ((const float4*)(feat + (size_t)s0 * D_FEAT))[lane];
    float4 v1 = ((const float4*)(feat + (size_t)s1 * D_FEAT))[lane];
    a0.x += v0.x; a0.y += v0.y; a0.z += v0.z; a0.w += v0.w;
    a1.x += v1.x; a1.y += v1.y; a1.z += v1.z; a1.w += v1.w;
  }
  if (j < n){
    int s0 = esrc[beg + j];
    float4 v0 = ((const float4*)(feat + (size_t)s0 * D_FEAT))[lane];
    a0.x += v0.x; a0.y += v0.y; a0.z += v0.z; a0.w += v0.w;
  }
  float inv = 1.0f / fmaxf((float)n, 1.0f);
  short4v o;
  o[0] = (short)f2bf((a0.x + a1.x) * inv);
  o[1] = (short)f2bf((a0.y + a1.y) * inv);
  o[2] = (short)f2bf((a0.z + a1.z) * inv);
  o[3] = (short)f2bf((a0.w + a1.w) * inv);
  ((short4v*)(mean + (size_t)row * D_FEAT))[lane] = o;
}

// ---------------- Fused MLP: out = [LN]( resid + relu(concat(h,s)@W1+b1)@W2 + b2 ) ----------------
// Block: 64 rows x 256 cols, 256 threads (4 waves). LDS = 52 KB -> 3 blocks/CU.
// R3 structure (reg-prefetch crossing barriers, 2 barriers/step, XOR-swizzled LDS)
// + 2-deep A prefetch (two named reg sets, 2-step-unrolled phase-1) to cover HBM latency
// + phase-2's first B loads issued before the hidden-spill VALU block.
template<int HAS_LN>
__global__ __launch_bounds__(256, 3) void fused_mlp_kernel(
    const float* __restrict__ h, const u16* __restrict__ s,
    const u16* __restrict__ B1t, const float* __restrict__ b1,
    const u16* __restrict__ B2t, const float* __restrict__ b2,
    const float* __restrict__ resid,
    const float* __restrict__ lng, const float* __restrict__ lnb,
    float* __restrict__ out, int M)
{
  __shared__ __align__(16) char smem_raw[53248];
  short8* As8 = (short8*)smem_raw;               // [64*4]   4096 B
  short8* Bs8 = (short8*)(smem_raw + 4096);      // [256*4] 16384 B
  u16*    hid = (u16*)(smem_raw + 20480);        // [64*256] 32768 B (swizzled)
  float*  part = (float*)smem_raw;               // aliases As8 (dead in epilogue): [2][64][4]

  int tid = threadIdx.x;
  int wave = tid >> 6, lane = tid & 63;
  int half = lane >> 4, l16 = lane & 15;
  int wc = wave * 64;
  int row0 = blockIdx.x * 64;

  // staging coords: A = 64 rows x 4 chunks (1/thread); B = 256 rows x 4 chunks (4/thread)
  int rA = tid >> 2, uA = tid & 3;
  int rgA = row0 + rA;
  bool rAok = rgA < M;
  int aw_idx = (rA << 2) | (uA ^ (rA & 3));      // swizzled A write slot

  floatx4 acc[4][4];
  floatx4 zero4 = {0.f, 0.f, 0.f, 0.f};
#pragma unroll
  for (int i = 0; i < 4; i++)
#pragma unroll
    for (int j = 0; j < 4; j++) acc[i][j] = zero4;

  short8 zero8 = {0,0,0,0,0,0,0,0};
  // 2-deep A prefetch register sets (named, static indexing - rule #20)
  float4 paA0 = {0.f,0.f,0.f,0.f}, paA1 = {0.f,0.f,0.f,0.f};
  float4 paB0 = {0.f,0.f,0.f,0.f}, paB1 = {0.f,0.f,0.f,0.f};
  short8 psA = zero8, psB = zero8;
  short8 pbv[4];

  // ---- phase 1 prologue: A set-A <- step0, A set-B <- step1, B <- step0 ----
  if (rAok){
    const float* src = h + (size_t)rgA * 256 + uA * 8;
    paA0 = ((const float4*)src)[0];
    paA1 = ((const float4*)src)[1];
    const float* src2 = h + (size_t)rgA * 256 + 32 + uA * 8;
    paB0 = ((const float4*)src2)[0];
    paB1 = ((const float4*)src2)[1];
  }
#pragma unroll
  for (int cc = 0; cc < 4; cc++){
    int c = tid + cc * 256;
    int r = c >> 2, u = c & 3;
    pbv[cc] = *(const short8*)(B1t + (size_t)r * 512 + u * 8);
  }

  // ---- phase 1: hidden = relu(concat(h,s) @ W1 + b1), K=512 ----
  // 2-step-unrolled: even step consumes set-A / issues set-A for k0+64;
  //                  odd  step consumes set-B / issues set-B for k0+96.
  for (int k0 = 0; k0 < 512; k0 += 64){
    // ======== even step (k0) ========
    {
      short8 va = zero8;
      if (rAok) va = (k0 < 256) ? pack8(paA0, paA1) : psA;
      As8[aw_idx] = va;
    }
#pragma unroll
    for (int cc = 0; cc < 4; cc++){
      int c = tid + cc * 256;
      int r = c >> 2, u = c & 3;
      Bs8[(r << 2) | (u ^ (r & 3))] = pbv[cc];
    }
    __syncthreads();

    {
      int k2 = k0 + 64;                  // A set-A two steps ahead
      if (k2 < 512 && rAok){
        int kk = k2 + uA * 8;
        if (k2 < 256){
          const float* src = h + (size_t)rgA * 256 + kk;
          paA0 = ((const float4*)src)[0];
          paA1 = ((const float4*)src)[1];
        } else {
          psA = *(const short8*)(s + (size_t)rgA * 256 + (kk - 256));
        }
      }
      int k1 = k0 + 32;                  // B one step ahead
#pragma unroll
      for (int cc = 0; cc < 4; cc++){
        int c = tid + cc * 256;
        int r = c >> 2, u = c & 3;
        pbv[cc] = *(const short8*)(B1t + (size_t)r * 512 + k1 + u * 8);
      }
    }

    {
      short8 af[4], bfr[4];
#pragma unroll
      for (int t = 0; t < 4; t++){
        int ra = t * 16 + l16;
        af[t] = As8[(ra << 2) | (half ^ (ra & 3))];
        int rb = wc + t * 16 + l16;
        bfr[t] = Bs8[(rb << 2) | (half ^ (rb & 3))];
      }
#pragma unroll
      for (int i = 0; i < 4; i++)
#pragma unroll
        for (int j = 0; j < 4; j++)
          acc[i][j] = __builtin_amdgcn_mfma_f32_16x16x32_bf16(af[i], bfr[j], acc[i][j], 0, 0, 0);
    }
    __syncthreads();

    // ======== odd step (k0+32) ========
    {
      int ko = k0 + 32;
      short8 va = zero8;
      if (rAok) va = (ko < 256) ? pack8(paB0, paB1) : psB;
      As8[aw_idx] = va;
    }
#pragma unroll
    for (int cc = 0; cc < 4; cc++){
      int c = tid + cc * 256;
      int r = c >> 2, u = c & 3;
      Bs8[(r << 2) | (u ^ (r & 3))] = pbv[cc];
    }
    __syncthreads();

    {
      int k2 = k0 + 96;                  // A set-B two steps ahead
      if (k2 < 512 && rAok){
        int kk = k2 + uA * 8;
        if (k2 < 256){
          const float* src = h + (size_t)rgA * 256 + kk;
          paB0 = ((const float4*)src)[0];
          paB1 = ((const float4*)src)[1];
        } else {
          psB = *(const short8*)(s + (size_t)rgA * 256 + (kk - 256));
        }
      }
      int k1 = k0 + 64;                  // B one step ahead
      if (k1 < 512){
#pragma unroll
        for (int cc = 0; cc < 4; cc++){
          int c = tid + cc * 256;
          int r = c >> 2, u = c & 3;
          pbv[cc] = *(const short8*)(B1t + (size_t)r * 512 + k1 + u * 8);
        }
      }
    }

    {
      short8 af[4], bfr[4];
#pragma unroll
      for (int t = 0; t < 4; t++){
        int ra = t * 16 + l16;
        af[t] = As8[(ra << 2) | (half ^ (ra & 3))];
        int rb = wc + t * 16 + l16;
        bfr[t] = Bs8[(rb << 2) | (half ^ (rb & 3))];
      }
#pragma unroll
      for (int i = 0; i < 4; i++)
#pragma unroll
        for (int j = 0; j < 4; j++)
          acc[i][j] = __builtin_amdgcn_mfma_f32_16x16x32_bf16(af[i], bfr[j], acc[i][j], 0, 0, 0);
    }
    __syncthreads();
  }

  // ---- phase transition: issue B2(step0) loads early (hide under hid spill) ----
#pragma unroll
  for (int cc = 0; cc < 4; cc++){
    int c = tid + cc * 256;
    int r = c >> 2, u = c & 3;
    pbv[cc] = *(const short8*)(B2t + (size_t)r * 256 + u * 8);
  }

  // hidden -> LDS (bias + relu + bf16), swizzled: chunk ^= row&7
#pragma unroll
  for (int i = 0; i < 4; i++){
#pragma unroll
    for (int j = 0; j < 4; j++){
      int cg = wc + j * 16 + l16;
      float bv = b1[cg];
#pragma unroll
      for (int r = 0; r < 4; r++){
        int lr = i * 16 + half * 4 + r;
        int idx = lr * 256 + ((((cg >> 3) ^ (lr & 7)) << 3) | (cg & 7));
        hid[idx] = f2bf(fmaxf(acc[i][j][r] + bv, 0.0f));
      }
    }
  }

#pragma unroll
  for (int i = 0; i < 4; i++)
#pragma unroll
    for (int j = 0; j < 4; j++) acc[i][j] = zero4;

  // ---- phase 2: out = hidden @ W2, K=256; A comes straight from hid LDS ----
  for (int k0 = 0; k0 < 256; k0 += 32){
#pragma unroll
    for (int cc = 0; cc < 4; cc++){
      int c = tid + cc * 256;
      int r = c >> 2, u = c & 3;
      Bs8[(r << 2) | (u ^ (r & 3))] = pbv[cc];
    }
    __syncthreads();                     // also orders hid writes before first reads

    if (k0 < 224){
      int k0n = k0 + 32;
#pragma unroll
      for (int cc = 0; cc < 4; cc++){
        int c = tid + cc * 256;
        int r = c >> 2, u = c & 3;
        pbv[cc] = *(const short8*)(B2t + (size_t)r * 256 + k0n + u * 8);
      }
    }

    short8 af[4], bfr[4];
#pragma unroll
    for (int t = 0; t < 4; t++){
      int ra = t * 16 + l16;
      int chunkL = (k0 >> 3) + half;
      af[t] = *(const short8*)(hid + ra * 256 + ((chunkL ^ (ra & 7)) << 3));
      int rb = wc + t * 16 + l16;
      bfr[t] = Bs8[(rb << 2) | (half ^ (rb & 3))];
    }
#pragma unroll
    for (int i = 0; i < 4; i++)
#pragma unroll
      for (int j = 0; j < 4; j++)
        acc[i][j] = __builtin_amdgcn_mfma_f32_16x16x32_bf16(af[i], bfr[j], acc[i][j], 0, 0, 0);
    __syncthreads();
  }

  // ---- epilogue: bias + residual ----
#pragma unroll
  for (int i = 0; i < 4; i++){
#pragma unroll
    for (int j = 0; j < 4; j++){
      int cg = wc + j * 16 + l16;
      float bv = b2[cg];
#pragma unroll
      for (int r = 0; r < 4; r++){
        int lr = i * 16 + half * 4 + r;
        int rg = row0 + lr;
        float rv = (rg < M) ? resid[(size_t)rg * 256 + cg] : 0.0f;
        acc[i][j][r] = acc[i][j][r] + bv + rv;
      }
    }
  }

  if (HAS_LN){
#pragma unroll
    for (int i = 0; i < 4; i++){
#pragma unroll
      for (int r = 0; r < 4; r++){
        float s1 = 0.f, s2 = 0.f;
#pragma unroll
        for (int j = 0; j < 4; j++){
          float v = acc[i][j][r];
          s1 += v; s2 += v * v;
        }
#pragma unroll
        for (int m = 1; m < 16; m <<= 1){
          s1 += __shfl_xor(s1, m, 64);
          s2 += __shfl_xor(s2, m, 64);
        }
        if (l16 == 0){
          int lr = i * 16 + half * 4 + r;
          part[lr * 4 + wave]       = s1;
          part[256 + lr * 4 + wave] = s2;
        }
      }
    }
    __syncthreads();
#pragma unroll
    for (int i = 0; i < 4; i++){
#pragma unroll
      for (int r = 0; r < 4; r++){
        int lr = i * 16 + half * 4 + r;
        int rg = row0 + lr;
        float4 p1 = *(const float4*)(part + lr * 4);
        float4 p2 = *(const float4*)(part + 256 + lr * 4);
        float su = p1.x + p1.y + p1.z + p1.w;
        float sq = p2.x + p2.y + p2.z + p2.w;
        float mean = su * (1.0f / 256.0f);
        float var = sq * (1.0f / 256.0f) - mean * mean;
        float rs = rsqrtf(var + 1e-5f);
        if (rg < M){
#pragma unroll
          for (int j = 0; j < 4; j++){
            int cg = wc + j * 16 + l16;
            float vv = (acc[i][j][r] - mean) * rs * lng[cg] + lnb[cg];
            out[(size_t)rg * 256 + cg] = vv;
          }
        }
      }
    }
  } else {
#pragma unroll
    for (int i = 0; i < 4; i++){
#pragma unroll
      for (int r = 0; r < 4; r++){
        int lr = i * 16 + half * 4 + r;
        int rg = row0 + lr;
        if (rg < M){
#pragma unroll
          for (int j = 0; j < 4; j++){
            int cg = wc + j * 16 + l16;
            out[(size_t)rg * 256 + cg] = acc[i][j][r];
          }
        }
      }
    }
  }
}

// helper: build CSR + aggregate mean for one stage
static void run_agg(const float* feat, const int* edge, int E, int Ndst,
                    int* cnt, int* row_start, int* fillc, int* bsums, int* esrc,
                    u16* mean, hipStream_t stream){
  const int* sidx = edge;
  const int* didx = edge + E;
  hipMemsetAsync(cnt, 0, (size_t)Ndst * 4, stream);
  int egrid = (E + 255) / 256;
  hist_kernel<<<egrid, 256, 0, stream>>>(didx, E, cnt);
  int nb = (Ndst + 255) / 256;
  scan_block_kernel<<<nb, 256, 0, stream>>>(cnt, row_start, bsums, Ndst);
  scan_bsums_kernel<<<1, 512, 0, stream>>>(bsums, nb);
  scan_add_kernel<<<nb, 256, 0, stream>>>(row_start, bsums, fillc, Ndst);
  fill_csr_kernel<<<egrid, 256, 0, stream>>>(sidx, didx, E, fillc, esrc);
  agg_mean_kernel<<<(Ndst + 3) / 4, 256, 0, stream>>>(feat, row_start, cnt, esrc, mean, Ndst);
}

extern "C" void kernel_launch(void* const* d_in, const int* in_sizes, int n_in,
                              void* d_out, int out_size, void* d_ws, size_t ws_size,
                              hipStream_t stream){
  const float* cell_h = (const float*)d_in[0];
  const float* net_h  = (const float*)d_in[1];
  const int* e_c2n = (const int*)d_in[2];
  const int* e_n2c = (const int*)d_in[3];
  const int* e_c2c = (const int*)d_in[4];
  const float* w1p[3] = {(const float*)d_in[5], (const float*)d_in[9],  (const float*)d_in[13]};
  const float* b1p[3] = {(const float*)d_in[6], (const float*)d_in[10], (const float*)d_in[14]};
  const float* w2p[3] = {(const float*)d_in[7], (const float*)d_in[11], (const float*)d_in[15]};
  const float* b2p[3] = {(const float*)d_in[8], (const float*)d_in[12], (const float*)d_in[16]};
  const float* net_g  = (const float*)d_in[17];
  const float* net_b  = (const float*)d_in[18];
  const float* cell_g = (const float*)d_in[19];
  const float* cell_b = (const float*)d_in[20];

  int n_cell = in_sizes[0] / 256;
  int n_net  = in_sizes[1] / 256;
  int E = in_sizes[2] / 2;

  float* cell_out = (float*)d_out;
  float* net_out  = (float*)d_out + (size_t)n_cell * 256;

  // workspace layout
  char* p = (char*)d_ws;
  u16* w1t[3]; u16* w2t[3];
  for (int i = 0; i < 3; i++){
    w1t[i] = (u16*)p; p += (size_t)512 * 256 * 2;
    w2t[i] = (u16*)p; p += (size_t)256 * 256 * 2;
  }
  u16* Mbuf = (u16*)p; p += (size_t)n_cell * 256 * 2;  // bf16 mean
  int n_pad = ((n_cell + 63) / 64) * 64;
  int* cnt       = (int*)p; p += (size_t)n_pad * 4;
  int* row_start = (int*)p; p += (size_t)n_pad * 4;
  int* fillc     = (int*)p; p += (size_t)n_pad * 4;
  int* bsums     = (int*)p; p += 1024 * 4;
  int* esrc      = (int*)p; p += (size_t)E * 4;

  // convert + transpose weights to bf16 [N][K]
  for (int i = 0; i < 3; i++){
    conv_t_kernel<<<(512 * 256 + 255) / 256, 256, 0, stream>>>(w1p[i], w1t[i], 512, 256);
    conv_t_kernel<<<(256 * 256 + 255) / 256, 256, 0, stream>>>(w2p[i], w2t[i], 256, 256);
  }

  dim3 blk(256);

  // ---- stage 1: cells -> nets (LN) ----
  run_agg(cell_h, e_c2n, E, n_net, cnt, row_start, fillc, bsums, esrc, Mbuf, stream);
  fused_mlp_kernel<1><<<dim3((n_net + 63) / 64), blk, 0, stream>>>(
      net_h, Mbuf, w1t[0], b1p[0], w2t[0], b2p[0], net_h, net_g, net_b, net_out, n_net);

  // ---- stage 2: nets -> cells (no LN) ----
  run_agg(net_out, e_n2c, E, n_cell, cnt, row_start, fillc, bsums, esrc, Mbuf, stream);
  fused_mlp_kernel<0><<<dim3((n_cell + 63) / 64), blk, 0, stream>>>(
      cell_h, Mbuf, w1t[1], b1p[1], w2t[1], b2p[1], cell_h, nullptr, nullptr, cell_out, n_cell);

  // ---- stage 3: cells -> cells (LN), in-place on cell_out ----
  run_agg(cell_out, e_c2c, E, n_cell, cnt, row_start, fillc, bsums, esrc, Mbuf, stream);
  fused_mlp_kernel<1><<<dim3((n_cell + 63) / 64), blk, 0, stream>>>(
      cell_out, Mbuf, w1t[2], b1p[2], w2t[2], b2p[2], cell_out, cell_g, cell_b, cell_out, n_cell);
}